// Round 4
// baseline (2812.087 us; speedup 1.0000x reference)
//
#include <hip/hip_runtime.h>
#include <hip/hip_bf16.h>
#include <cmath>

#define N_ATOMS 20000
#define NE      320000
#define FDIM    64
#define NRBF    32

__device__ __forceinline__ float silu(float x) {
    return x / (1.0f + __expf(-x));
}

// ---------------- transpose wtT[k][f][g] from Wt[k][g][f] ----------------
__global__ void transpose_kernel(const float* __restrict__ Wt, float* __restrict__ wtT) {
    int idx = blockIdx.x * 256 + threadIdx.x;
    if (idx >= 24576) return;
    int k = idx >> 12;
    int r = idx & 4095;
    int g = r >> 6;
    int f = r & 63;
    wtT[k * 4096 + f * 64 + g] = Wt[idx];
}

// ---------------- CSR build ----------------
__global__ void hist_kernel(const int* __restrict__ dst, int* __restrict__ deg) {
    int e = blockIdx.x * 256 + threadIdx.x;
    if (e >= NE) return;
    atomicAdd(&deg[dst[e]], 1);
}

__global__ void scan_kernel(const int* __restrict__ deg, int* __restrict__ off) {
    __shared__ int part[1024];
    int t = threadIdx.x;
    const int CH = (N_ATOMS + 1023) / 1024; // 20
    int base = t * CH;
    int s = 0;
    for (int i = 0; i < CH; i++) {
        int idx = base + i;
        if (idx < N_ATOMS) s += deg[idx];
    }
    part[t] = s;
    __syncthreads();
    for (int ofs = 1; ofs < 1024; ofs <<= 1) {
        int v = (t >= ofs) ? part[t - ofs] : 0;
        __syncthreads();
        part[t] += v;
        __syncthreads();
    }
    int run = (t == 0) ? 0 : part[t - 1];
    for (int i = 0; i < CH; i++) {
        int idx = base + i;
        if (idx < N_ATOMS) {
            off[idx] = run;
            run += deg[idx];
        }
    }
    if (t == 1023) off[N_ATOMS] = run;
}

__global__ void fill_kernel(const int* __restrict__ dst, const int* __restrict__ srcArr,
                            const int* __restrict__ off, int* __restrict__ cursor,
                            int* __restrict__ ebkt, int* __restrict__ sbkt) {
    int e = blockIdx.x * 256 + threadIdx.x;
    if (e >= NE) return;
    int d = dst[e];
    int pos = atomicAdd(&cursor[d], 1);
    ebkt[off[d] + pos] = e;
    sbkt[off[d] + pos] = srcArr[e];
}

// ---------------- edge MLP: thread per edge, wave-uniform weight reads ----------------
// __launch_bounds__(256,1): allocator free up to 256 VGPRs; peak live set is
// h1[64]+h2[128]+temps ~ 210 -> must NOT spill (round-3 spilled at the 128 cap:
// FETCH 1.22 GB of scratch traffic, VALUBusy 20%).
__global__ __launch_bounds__(256, 1) void mlp_kernel(
    const float* __restrict__ rfv, const float* __restrict__ dij,
    const float* __restrict__ W0, const float* __restrict__ b0,
    const float* __restrict__ W1, const float* __restrict__ b1,
    const float* __restrict__ W2, const float* __restrict__ b2,
    __hip_bfloat16* __restrict__ r) {
    int e = blockIdx.x * 256 + threadIdx.x;

    float in[32];
    const float4* rp = (const float4*)(rfv + (size_t)e * 32);
#pragma unroll
    for (int i = 0; i < 8; i++) {
        float4 v = rp[i];
        in[4 * i + 0] = v.x; in[4 * i + 1] = v.y;
        in[4 * i + 2] = v.z; in[4 * i + 3] = v.w;
    }

    // layer 1: 32 -> 64 (W0 index wave-uniform -> s_load)
    float h1[64];
#pragma unroll
    for (int g = 0; g < 64; g++) {
        float acc = b0[g];
#pragma unroll
        for (int k = 0; k < 32; k++) acc += in[k] * W0[g * 32 + k];
        h1[g] = silu(acc);
    }

    // layer 2: 64 -> 128
    float h2[128];
#pragma unroll
    for (int g = 0; g < 128; g++) {
        float acc = b1[g];
#pragma unroll
        for (int k = 0; k < 64; k++) acc += h1[k] * W1[g * 64 + k];
        h2[g] = silu(acc);
    }

    float d = dij[e];
    float C = (d < 1.0f) ? 0.5f * (__cosf(3.14159265358979323846f * d) + 1.0f) : 0.0f;

    // layer 3: 128 -> 192, dynamic f loop (6 independent FMA chains)
    __hip_bfloat16* rout = r + (size_t)e * 192;
    for (int f = 0; f < 64; f += 2) {
        float a0 = b2[3 * f + 0], a1 = b2[3 * f + 1], a2 = b2[3 * f + 2];
        float a3 = b2[3 * f + 3], a4 = b2[3 * f + 4], a5 = b2[3 * f + 5];
#pragma unroll
        for (int k = 0; k < 128; k++) {
            float h = h2[k];
            a0 += h * W2[(3 * f + 0) * 128 + k];
            a1 += h * W2[(3 * f + 1) * 128 + k];
            a2 += h * W2[(3 * f + 2) * 128 + k];
            a3 += h * W2[(3 * f + 3) * 128 + k];
            a4 += h * W2[(3 * f + 4) * 128 + k];
            a5 += h * W2[(3 * f + 5) * 128 + k];
        }
        rout[3 * f + 0] = __float2bfloat16(silu(a0) * C);
        rout[3 * f + 1] = __float2bfloat16(silu(a1) * C);
        rout[3 * f + 2] = __float2bfloat16(silu(a2) * C);
        rout[3 * f + 3] = __float2bfloat16(silu(a3) * C);
        rout[3 * f + 4] = __float2bfloat16(silu(a4) * C);
        rout[3 * f + 5] = __float2bfloat16(silu(a5) * C);
    }
}

// ---------------- fused decompose + lin1 ----------------
__global__ __launch_bounds__(256) void lin1_kernel(
    const float* __restrict__ X, const float* __restrict__ wtT,
    float* __restrict__ comp, float* __restrict__ Yb) {
    __shared__ float lds[4][64 * 11];
    int w = threadIdx.x >> 6;
    int l = threadIdx.x & 63;
    int a = blockIdx.x * 4 + w;

    {
        const float* x = X + ((size_t)a * 64 + l) * 9;
        float v[9];
#pragma unroll
        for (int i = 0; i < 9; i++) v[i] = x[i];
        float t2 = 0.f;
#pragma unroll
        for (int i = 0; i < 9; i++) t2 += v[i] * v[i];
        float inv = 1.0f / (t2 + 1.0f);
#pragma unroll
        for (int i = 0; i < 9; i++) v[i] *= inv;
        float iso = (v[0] + v[4] + v[8]) * (1.0f / 3.0f);
        float* o = &lds[w][l * 11];
        o[0] = iso;
        o[1] = 0.5f * (v[1] - v[3]);
        o[2] = 0.5f * (v[2] - v[6]);
        o[3] = 0.5f * (v[5] - v[7]);
        o[4] = v[0] - iso;
        o[5] = 0.5f * (v[1] + v[3]);
        o[6] = 0.5f * (v[2] + v[6]);
        o[7] = v[4] - iso;
        o[8] = 0.5f * (v[5] + v[7]);
        o[9] = v[8] - iso;
    }
    __syncthreads();
    {
        int g = l;
        const float* w0 = wtT;
        const float* w1 = wtT + 4096;
        const float* w2 = wtT + 8192;
        float acc[10];
#pragma unroll
        for (int c = 0; c < 10; c++) acc[c] = 0.f;
        for (int f = 0; f < 64; f++) {
            float wI = w0[f * 64 + g];
            float wA = w1[f * 64 + g];
            float wS = w2[f * 64 + g];
            const float* rf = &lds[w][f * 11];
            acc[0] += wI * rf[0];
            acc[1] += wA * rf[1];
            acc[2] += wA * rf[2];
            acc[3] += wA * rf[3];
#pragma unroll
            for (int c = 4; c < 10; c++) acc[c] += wS * rf[c];
        }
        float* co = comp + ((size_t)a * 64 + g) * 10;
#pragma unroll
        for (int c = 0; c < 10; c++) co[c] = acc[c];
        float* y = Yb + ((size_t)a * 64 + g) * 9;
        y[0] = acc[0] + acc[4];
        y[1] = acc[5] + acc[1];
        y[2] = acc[6] + acc[2];
        y[3] = acc[5] - acc[1];
        y[4] = acc[0] + acc[7];
        y[5] = acc[8] + acc[3];
        y[6] = acc[6] - acc[2];
        y[7] = acc[8] - acc[3];
        y[8] = acc[0] + acc[9];
    }
}

// ---------------- message passing: CSR gather, wave per atom, lane = feature ----------------
__global__ __launch_bounds__(256) void msg_kernel(
    const int* __restrict__ off, const int* __restrict__ ebkt,
    const int* __restrict__ sbkt, const __hip_bfloat16* __restrict__ r,
    const float* __restrict__ comp, float* __restrict__ msg) {
    int a = blockIdx.x * 4 + (threadIdx.x >> 6);
    int l = threadIdx.x & 63;
    int beg = off[a], end = off[a + 1];
    float acc[10];
#pragma unroll
    for (int c = 0; c < 10; c++) acc[c] = 0.f;
    for (int i = beg; i < end; i++) {
        int e = ebkt[i];
        int s = sbkt[i];
        const __hip_bfloat16* rp = r + (size_t)e * 192 + l * 3;
        float r0 = __bfloat162float(rp[0]);
        float r1 = __bfloat162float(rp[1]);
        float r2 = __bfloat162float(rp[2]);
        const float* cp = comp + ((size_t)s * 64 + l) * 10;
        acc[0] += r0 * cp[0];
        acc[1] += r1 * cp[1];
        acc[2] += r1 * cp[2];
        acc[3] += r1 * cp[3];
#pragma unroll
        for (int c = 4; c < 10; c++) acc[c] += r2 * cp[c];
    }
    float* m = msg + ((size_t)a * 64 + l) * 10;
#pragma unroll
    for (int c = 0; c < 10; c++) m[c] = acc[c];
}

// ---------------- fused pair + lin2 + epilogue ----------------
__global__ __launch_bounds__(256) void lin2_kernel(
    const float* __restrict__ msg, const float* __restrict__ Yb,
    const float* __restrict__ X, const float* __restrict__ charges,
    const float* __restrict__ wtT, float* __restrict__ out) {
    __shared__ float lds[4][64 * 11];
    int w = threadIdx.x >> 6;
    int l = threadIdx.x & 63;
    int a = blockIdx.x * 4 + w;
    float q = 1.0f + 0.1f * charges[a];

    {
        const float* mc = msg + ((size_t)a * 64 + l) * 10;
        float m0 = mc[0], m1 = mc[1], m2 = mc[2], m3 = mc[3], m4 = mc[4],
              m5 = mc[5], m6 = mc[6], m7 = mc[7], m8 = mc[8], m9 = mc[9];
        float M[9];
        M[0] = m0 + m4; M[1] = m5 + m1; M[2] = m6 + m2;
        M[3] = m5 - m1; M[4] = m0 + m7; M[5] = m8 + m3;
        M[6] = m6 - m2; M[7] = m8 - m3; M[8] = m0 + m9;
        const float* yp = Yb + ((size_t)a * 64 + l) * 9;
        float Y[9];
#pragma unroll
        for (int i = 0; i < 9; i++) Y[i] = yp[i];
        float P[9];
#pragma unroll
        for (int i = 0; i < 3; i++) {
#pragma unroll
            for (int j = 0; j < 3; j++) {
                float s = 0.f;
#pragma unroll
                for (int k = 0; k < 3; k++)
                    s += M[i * 3 + k] * Y[k * 3 + j] + Y[i * 3 + k] * M[k * 3 + j];
                P[i * 3 + j] = q * s;
            }
        }
        float t2 = 0.f;
#pragma unroll
        for (int i = 0; i < 9; i++) t2 += P[i] * P[i];
        float inv = 1.0f / (t2 + 1.0f);
        float iso = (P[0] + P[4] + P[8]) * (1.0f / 3.0f);
        float* o = &lds[w][l * 11];
        o[0] = iso * inv;
        o[1] = 0.5f * (P[1] - P[3]) * inv;
        o[2] = 0.5f * (P[2] - P[6]) * inv;
        o[3] = 0.5f * (P[5] - P[7]) * inv;
        o[4] = (P[0] - iso) * inv;
        o[5] = 0.5f * (P[1] + P[3]) * inv;
        o[6] = 0.5f * (P[2] + P[6]) * inv;
        o[7] = (P[4] - iso) * inv;
        o[8] = 0.5f * (P[5] + P[7]) * inv;
        o[9] = (P[8] - iso) * inv;
    }
    __syncthreads();
    {
        int g = l;
        const float* w3 = wtT + 3 * 4096;
        const float* w4 = wtT + 4 * 4096;
        const float* w5 = wtT + 5 * 4096;
        float acc[10];
#pragma unroll
        for (int c = 0; c < 10; c++) acc[c] = 0.f;
        for (int f = 0; f < 64; f++) {
            float wI = w3[f * 64 + g];
            float wA = w4[f * 64 + g];
            float wS = w5[f * 64 + g];
            const float* rf = &lds[w][f * 11];
            acc[0] += wI * rf[0];
            acc[1] += wA * rf[1];
            acc[2] += wA * rf[2];
            acc[3] += wA * rf[3];
#pragma unroll
            for (int c = 4; c < 10; c++) acc[c] += wS * rf[c];
        }
        float D[9];
        D[0] = acc[0] + acc[4]; D[1] = acc[5] + acc[1]; D[2] = acc[6] + acc[2];
        D[3] = acc[5] - acc[1]; D[4] = acc[0] + acc[7]; D[5] = acc[8] + acc[3];
        D[6] = acc[6] - acc[2]; D[7] = acc[8] - acc[3]; D[8] = acc[0] + acc[9];

        const float* x = X + ((size_t)a * 64 + g) * 9;
        float xv[9];
#pragma unroll
        for (int i = 0; i < 9; i++) xv[i] = x[i];
        float t2 = 0.f;
#pragma unroll
        for (int i = 0; i < 9; i++) t2 += xv[i] * xv[i];
        float invn = 1.0f / (t2 + 1.0f);
#pragma unroll
        for (int i = 0; i < 9; i++) xv[i] *= invn;

        float DD[9];
#pragma unroll
        for (int i = 0; i < 3; i++) {
#pragma unroll
            for (int j = 0; j < 3; j++) {
                float s = 0.f;
#pragma unroll
                for (int k = 0; k < 3; k++) s += D[i * 3 + k] * D[k * 3 + j];
                DD[i * 3 + j] = s;
            }
        }
        float* op = out + ((size_t)a * 64 + g) * 9;
#pragma unroll
        for (int i = 0; i < 9; i++) op[i] = xv[i] + D[i] + q * DD[i];
    }
}

extern "C" void kernel_launch(void* const* d_in, const int* in_sizes, int n_in,
                              void* d_out, int out_size, void* d_ws, size_t ws_size,
                              hipStream_t stream) {
    const float* X       = (const float*)d_in[0];
    const int*   pair    = (const int*)d_in[1];
    const float* dij     = (const float*)d_in[2];
    const float* rfv     = (const float*)d_in[3];
    const float* charges = (const float*)d_in[4];
    const float* W0      = (const float*)d_in[5];
    const float* b0      = (const float*)d_in[6];
    const float* W1      = (const float*)d_in[7];
    const float* b1      = (const float*)d_in[8];
    const float* W2      = (const float*)d_in[9];
    const float* b2      = (const float*)d_in[10];
    const float* Wt      = (const float*)d_in[11];
    float* out = (float*)d_out;

    const int* dst = pair;        // pair_indices[0] (scatter)
    const int* src = pair + NE;   // pair_indices[1] (gather)

    // ---- workspace layout (~227 MB) ----
    char* ws = (char*)d_ws;
    size_t ofs = 0;
    auto alloc = [&](size_t bytes) {
        void* p = ws + ofs;
        ofs += (bytes + 255) & ~(size_t)255;
        return p;
    };
    float* wtT  = (float*)alloc((size_t)6 * 4096 * 4);                 // 96 KB
    float* comp = (float*)alloc((size_t)N_ATOMS * FDIM * 10 * 4);      // 51.2 MB
    float* msg  = (float*)alloc((size_t)N_ATOMS * FDIM * 10 * 4);      // 51.2 MB
    __hip_bfloat16* rbuf = (__hip_bfloat16*)alloc((size_t)NE * 192 * 2); // 122.9 MB
    int* deg    = (int*)alloc((size_t)N_ATOMS * 4);
    int* offarr = (int*)alloc((size_t)(N_ATOMS + 1) * 4);
    int* cursor = (int*)alloc((size_t)N_ATOMS * 4);
    int* ebkt   = (int*)alloc((size_t)NE * 4);
    int* sbkt   = (int*)alloc((size_t)NE * 4);
    float* Yb   = out;  // reuse d_out as Y scratch; fully overwritten by lin2

    hipMemsetAsync(deg, 0, (size_t)N_ATOMS * 4, stream);
    hipMemsetAsync(cursor, 0, (size_t)N_ATOMS * 4, stream);

    transpose_kernel<<<(24576 + 255) / 256, 256, 0, stream>>>(Wt, wtT);
    hist_kernel<<<NE / 256, 256, 0, stream>>>(dst, deg);
    scan_kernel<<<1, 1024, 0, stream>>>(deg, offarr);
    fill_kernel<<<NE / 256, 256, 0, stream>>>(dst, src, offarr, cursor, ebkt, sbkt);

    mlp_kernel<<<NE / 256, 256, 0, stream>>>(rfv, dij, W0, b0, W1, b1, W2, b2, rbuf);

    lin1_kernel<<<N_ATOMS / 4, 256, 0, stream>>>(X, wtT, comp, Yb);

    msg_kernel<<<N_ATOMS / 4, 256, 0, stream>>>(offarr, ebkt, sbkt, rbuf, comp, msg);

    lin2_kernel<<<N_ATOMS / 4, 256, 0, stream>>>(msg, Yb, X, charges, wtT, out);
}

// Round 5
// 581.264 us; speedup vs baseline: 4.8379x; 4.8379x over previous
//
#include <hip/hip_runtime.h>
#include <hip/hip_bf16.h>
#include <cmath>

#define N_ATOMS 20000
#define NE      320000
#define FDIM    64
#define NRBF    32
#define PI_F    3.14159265358979323846f

typedef __attribute__((ext_vector_type(8))) short bf16x8;
typedef __attribute__((ext_vector_type(4))) float f32x4;

#define MFMA16(a, b, c) __builtin_amdgcn_mfma_f32_16x16x32_bf16(a, b, c, 0, 0, 0)

__device__ __forceinline__ float silu(float x) {
    return x / (1.0f + __expf(-x));
}

__device__ __forceinline__ unsigned short f2bf_rne(float x) {
    unsigned u = __float_as_uint(x);
    u += 0x7fffu + ((u >> 16) & 1u);
    return (unsigned short)(u >> 16);
}

// split fp32 -> hi (truncated bf16) + lo (RNE bf16 of residual); hi+lo ~ 2^-17 rel
__device__ __forceinline__ void split8(const float* v, bf16x8& hi, bf16x8& lo) {
#pragma unroll
    for (int j = 0; j < 8; j++) {
        unsigned u = __float_as_uint(v[j]);
        float hf = __uint_as_float(u & 0xffff0000u);
        hi[j] = (short)(u >> 16);
        lo[j] = (short)f2bf_rne(v[j] - hf);
    }
}

// ---------------- transpose wtT[k][f][g] from Wt[k][g][f] ----------------
__global__ void transpose_kernel(const float* __restrict__ Wt, float* __restrict__ wtT) {
    int idx = blockIdx.x * 256 + threadIdx.x;
    if (idx >= 24576) return;
    int k = idx >> 12;
    int r = idx & 4095;
    int g = r >> 6;
    int f = r & 63;
    wtT[k * 4096 + f * 64 + g] = Wt[idx];
}

// ---------------- weight fragment prep: hi/lo bf16 planes, MFMA B-layout ----------------
// frag index t = ((ks*NT + nt)*64 + lane)*8 + j ; element = W[n*K + k],
// n = nt*16 + (lane&15), k = ks*32 + (lane>>4)*8 + j.
__global__ void wfrag_kernel(const float* __restrict__ W0, const float* __restrict__ W1,
                             const float* __restrict__ W2,
                             unsigned short* __restrict__ f0h, unsigned short* __restrict__ f0l,
                             unsigned short* __restrict__ f1h, unsigned short* __restrict__ f1l,
                             unsigned short* __restrict__ f2h, unsigned short* __restrict__ f2l) {
    int idx = blockIdx.x * 256 + threadIdx.x;
    const float* W;
    unsigned short *fh, *fl;
    int t, K, NT;
    if (idx < 2048)       { W = W0; fh = f0h; fl = f0l; t = idx;         K = 32;  NT = 4; }
    else if (idx < 10240) { W = W1; fh = f1h; fl = f1l; t = idx - 2048;  K = 64;  NT = 8; }
    else if (idx < 34816) { W = W2; fh = f2h; fl = f2l; t = idx - 10240; K = 128; NT = 12; }
    else return;
    int j = t & 7;
    int lane = (t >> 3) & 63;
    int rest = t >> 9;
    int nt = rest % NT;
    int ks = rest / NT;
    int k = ks * 32 + ((lane >> 4) & 3) * 8 + j;
    int n = nt * 16 + (lane & 15);
    float w = W[n * K + k];
    unsigned u = __float_as_uint(w);
    float hf = __uint_as_float(u & 0xffff0000u);
    fh[t] = (unsigned short)(u >> 16);
    fl[t] = f2bf_rne(w - hf);
}

// ---------------- CSR build ----------------
__global__ void hist_kernel(const int* __restrict__ dst, int* __restrict__ deg) {
    int e = blockIdx.x * 256 + threadIdx.x;
    if (e >= NE) return;
    atomicAdd(&deg[dst[e]], 1);
}

__global__ void scan_kernel(const int* __restrict__ deg, int* __restrict__ off) {
    __shared__ int part[1024];
    int t = threadIdx.x;
    const int CH = (N_ATOMS + 1023) / 1024; // 20
    int base = t * CH;
    int s = 0;
    for (int i = 0; i < CH; i++) {
        int idx = base + i;
        if (idx < N_ATOMS) s += deg[idx];
    }
    part[t] = s;
    __syncthreads();
    for (int ofs = 1; ofs < 1024; ofs <<= 1) {
        int v = (t >= ofs) ? part[t - ofs] : 0;
        __syncthreads();
        part[t] += v;
        __syncthreads();
    }
    int run = (t == 0) ? 0 : part[t - 1];
    for (int i = 0; i < CH; i++) {
        int idx = base + i;
        if (idx < N_ATOMS) {
            off[idx] = run;
            run += deg[idx];
        }
    }
    if (t == 1023) off[N_ATOMS] = run;
}

__global__ void fill_kernel(const int* __restrict__ dst, const int* __restrict__ srcArr,
                            const int* __restrict__ off, int* __restrict__ cursor,
                            int* __restrict__ ebkt, int* __restrict__ sbkt) {
    int e = blockIdx.x * 256 + threadIdx.x;
    if (e >= NE) return;
    int d = dst[e];
    int pos = atomicAdd(&cursor[d], 1);
    ebkt[off[d] + pos] = e;
    sbkt[off[d] + pos] = srcArr[e];
}

// ---------------- edge MLP via MFMA, 3-term bf16 split (~fp32 precision) ----------------
// block = 128 threads = 2 waves; wave handles 32 edges (2 M-tiles), no barriers
// (wave-private LDS). Layouts (m89/m91/m120-verified):
//   A: m = lane&15, k = quad*8+j ;  B: n = lane&15, k = quad*8+j ;
//   D: n = lane&15, m = quad*4+reg.
#define H1S 68   // 64 + 4 pad dwords: b128 A-reads uniform across bank windows
#define H2S 132  // 128 + 4 pad
__global__ __launch_bounds__(128) void mlp_mfma_kernel(
    const float* __restrict__ rfv, const float* __restrict__ dij,
    const float* __restrict__ b0, const float* __restrict__ b1, const float* __restrict__ b2,
    const unsigned short* __restrict__ f0h, const unsigned short* __restrict__ f0l,
    const unsigned short* __restrict__ f1h, const unsigned short* __restrict__ f1l,
    const unsigned short* __restrict__ f2h, const unsigned short* __restrict__ f2l,
    __hip_bfloat16* __restrict__ r) {
    __shared__ float h1s[2][32][H1S];
    __shared__ float h2s[2][32][H2S];
    const int w = threadIdx.x >> 6;
    const int lane = threadIdx.x & 63;
    const int q = lane >> 4;
    const int c = lane & 15;
    const int e0 = (blockIdx.x * 2 + w) * 32;
    float (*h1)[H1S] = h1s[w];
    float (*h2)[H2S] = h2s[w];

    // ---- layer 1: [32,32] x [32,64] -> h1 ----
    {
        bf16x8 ah[2], al[2];
#pragma unroll
        for (int mt = 0; mt < 2; mt++) {
            float v[8];
            const float* p = rfv + (size_t)(e0 + mt * 16 + c) * 32 + q * 8;
            *(float4*)(v)     = *(const float4*)(p);
            *(float4*)(v + 4) = *(const float4*)(p + 4);
            split8(v, ah[mt], al[mt]);
        }
#pragma unroll
        for (int nt = 0; nt < 4; nt++) {
            float bias = b0[nt * 16 + c];
            f32x4 acc[2];
            acc[0] = {bias, bias, bias, bias};
            acc[1] = acc[0];
            bf16x8 bh = *(const bf16x8*)(f0h + (size_t)(nt * 64 + lane) * 8);
            bf16x8 bl = *(const bf16x8*)(f0l + (size_t)(nt * 64 + lane) * 8);
#pragma unroll
            for (int mt = 0; mt < 2; mt++) {
                acc[mt] = MFMA16(al[mt], bh, acc[mt]);
                acc[mt] = MFMA16(ah[mt], bl, acc[mt]);
                acc[mt] = MFMA16(ah[mt], bh, acc[mt]);
            }
#pragma unroll
            for (int mt = 0; mt < 2; mt++)
#pragma unroll
                for (int reg = 0; reg < 4; reg++)
                    h1[mt * 16 + q * 4 + reg][nt * 16 + c] = silu(acc[mt][reg]);
        }
    }

    // ---- layer 2: [32,64] x [64,128] -> h2 ----
    {
        bf16x8 ah[2][2], al[2][2];
#pragma unroll
        for (int mt = 0; mt < 2; mt++)
#pragma unroll
            for (int ks = 0; ks < 2; ks++) {
                float v[8];
                const float* p = &h1[mt * 16 + c][ks * 32 + q * 8];
                *(float4*)(v)     = *(const float4*)(p);
                *(float4*)(v + 4) = *(const float4*)(p + 4);
                split8(v, ah[mt][ks], al[mt][ks]);
            }
#pragma unroll
        for (int nt = 0; nt < 8; nt++) {
            float bias = b1[nt * 16 + c];
            f32x4 acc[2];
            acc[0] = {bias, bias, bias, bias};
            acc[1] = acc[0];
#pragma unroll
            for (int ks = 0; ks < 2; ks++) {
                bf16x8 bh = *(const bf16x8*)(f1h + (size_t)((ks * 8 + nt) * 64 + lane) * 8);
                bf16x8 bl = *(const bf16x8*)(f1l + (size_t)((ks * 8 + nt) * 64 + lane) * 8);
#pragma unroll
                for (int mt = 0; mt < 2; mt++) {
                    acc[mt] = MFMA16(al[mt][ks], bh, acc[mt]);
                    acc[mt] = MFMA16(ah[mt][ks], bl, acc[mt]);
                    acc[mt] = MFMA16(ah[mt][ks], bh, acc[mt]);
                }
            }
#pragma unroll
            for (int mt = 0; mt < 2; mt++)
#pragma unroll
                for (int reg = 0; reg < 4; reg++)
                    h2[mt * 16 + q * 4 + reg][nt * 16 + c] = silu(acc[mt][reg]);
        }
    }

    // ---- layer 3: [32,128] x [128,192] -> r (silu * cutoff, bf16) ----
    {
        bf16x8 ah[2][4], al[2][4];
#pragma unroll
        for (int mt = 0; mt < 2; mt++)
#pragma unroll
            for (int ks = 0; ks < 4; ks++) {
                float v[8];
                const float* p = &h2[mt * 16 + c][ks * 32 + q * 8];
                *(float4*)(v)     = *(const float4*)(p);
                *(float4*)(v + 4) = *(const float4*)(p + 4);
                split8(v, ah[mt][ks], al[mt][ks]);
            }
        float cut[2][4];
#pragma unroll
        for (int mt = 0; mt < 2; mt++)
#pragma unroll
            for (int reg = 0; reg < 4; reg++) {
                float d = dij[e0 + mt * 16 + q * 4 + reg];
                cut[mt][reg] = (d < 1.0f) ? 0.5f * (__cosf(PI_F * d) + 1.0f) : 0.0f;
            }
#pragma unroll
        for (int nt = 0; nt < 12; nt++) {
            float bias = b2[nt * 16 + c];
            f32x4 acc[2];
            acc[0] = {bias, bias, bias, bias};
            acc[1] = acc[0];
#pragma unroll
            for (int ks = 0; ks < 4; ks++) {
                bf16x8 bh = *(const bf16x8*)(f2h + (size_t)((ks * 12 + nt) * 64 + lane) * 8);
                bf16x8 bl = *(const bf16x8*)(f2l + (size_t)((ks * 12 + nt) * 64 + lane) * 8);
#pragma unroll
                for (int mt = 0; mt < 2; mt++) {
                    acc[mt] = MFMA16(al[mt][ks], bh, acc[mt]);
                    acc[mt] = MFMA16(ah[mt][ks], bl, acc[mt]);
                    acc[mt] = MFMA16(ah[mt][ks], bh, acc[mt]);
                }
            }
#pragma unroll
            for (int mt = 0; mt < 2; mt++)
#pragma unroll
                for (int reg = 0; reg < 4; reg++)
                    r[(size_t)(e0 + mt * 16 + q * 4 + reg) * 192 + nt * 16 + c] =
                        __float2bfloat16(silu(acc[mt][reg]) * cut[mt][reg]);
        }
    }
}

// ---------------- fused decompose + lin1 ----------------
__global__ __launch_bounds__(256) void lin1_kernel(
    const float* __restrict__ X, const float* __restrict__ wtT,
    float* __restrict__ comp, float* __restrict__ Yb) {
    __shared__ float lds[4][64 * 11];
    int w = threadIdx.x >> 6;
    int l = threadIdx.x & 63;
    int a = blockIdx.x * 4 + w;

    {
        const float* x = X + ((size_t)a * 64 + l) * 9;
        float v[9];
#pragma unroll
        for (int i = 0; i < 9; i++) v[i] = x[i];
        float t2 = 0.f;
#pragma unroll
        for (int i = 0; i < 9; i++) t2 += v[i] * v[i];
        float inv = 1.0f / (t2 + 1.0f);
#pragma unroll
        for (int i = 0; i < 9; i++) v[i] *= inv;
        float iso = (v[0] + v[4] + v[8]) * (1.0f / 3.0f);
        float* o = &lds[w][l * 11];
        o[0] = iso;
        o[1] = 0.5f * (v[1] - v[3]);
        o[2] = 0.5f * (v[2] - v[6]);
        o[3] = 0.5f * (v[5] - v[7]);
        o[4] = v[0] - iso;
        o[5] = 0.5f * (v[1] + v[3]);
        o[6] = 0.5f * (v[2] + v[6]);
        o[7] = v[4] - iso;
        o[8] = 0.5f * (v[5] + v[7]);
        o[9] = v[8] - iso;
    }
    __syncthreads();
    {
        int g = l;
        const float* w0 = wtT;
        const float* w1 = wtT + 4096;
        const float* w2 = wtT + 8192;
        float acc[10];
#pragma unroll
        for (int c = 0; c < 10; c++) acc[c] = 0.f;
        for (int f = 0; f < 64; f++) {
            float wI = w0[f * 64 + g];
            float wA = w1[f * 64 + g];
            float wS = w2[f * 64 + g];
            const float* rf = &lds[w][f * 11];
            acc[0] += wI * rf[0];
            acc[1] += wA * rf[1];
            acc[2] += wA * rf[2];
            acc[3] += wA * rf[3];
#pragma unroll
            for (int c = 4; c < 10; c++) acc[c] += wS * rf[c];
        }
        float* co = comp + ((size_t)a * 64 + g) * 10;
#pragma unroll
        for (int c = 0; c < 10; c++) co[c] = acc[c];
        float* y = Yb + ((size_t)a * 64 + g) * 9;
        y[0] = acc[0] + acc[4];
        y[1] = acc[5] + acc[1];
        y[2] = acc[6] + acc[2];
        y[3] = acc[5] - acc[1];
        y[4] = acc[0] + acc[7];
        y[5] = acc[8] + acc[3];
        y[6] = acc[6] - acc[2];
        y[7] = acc[8] - acc[3];
        y[8] = acc[0] + acc[9];
    }
}

// ---------------- message passing: CSR gather, wave per atom, lane = feature ----------------
__global__ __launch_bounds__(256) void msg_kernel(
    const int* __restrict__ off, const int* __restrict__ ebkt,
    const int* __restrict__ sbkt, const __hip_bfloat16* __restrict__ r,
    const float* __restrict__ comp, float* __restrict__ msg) {
    int a = blockIdx.x * 4 + (threadIdx.x >> 6);
    int l = threadIdx.x & 63;
    int beg = off[a], end = off[a + 1];
    float acc[10];
#pragma unroll
    for (int c = 0; c < 10; c++) acc[c] = 0.f;
    for (int i = beg; i < end; i++) {
        int e = ebkt[i];
        int s = sbkt[i];
        const __hip_bfloat16* rp = r + (size_t)e * 192 + l * 3;
        float r0 = __bfloat162float(rp[0]);
        float r1 = __bfloat162float(rp[1]);
        float r2 = __bfloat162float(rp[2]);
        const float* cp = comp + ((size_t)s * 64 + l) * 10;
        acc[0] += r0 * cp[0];
        acc[1] += r1 * cp[1];
        acc[2] += r1 * cp[2];
        acc[3] += r1 * cp[3];
#pragma unroll
        for (int c = 4; c < 10; c++) acc[c] += r2 * cp[c];
    }
    float* m = msg + ((size_t)a * 64 + l) * 10;
#pragma unroll
    for (int c = 0; c < 10; c++) m[c] = acc[c];
}

// ---------------- fused pair + lin2 + epilogue ----------------
__global__ __launch_bounds__(256) void lin2_kernel(
    const float* __restrict__ msg, const float* __restrict__ Yb,
    const float* __restrict__ X, const float* __restrict__ charges,
    const float* __restrict__ wtT, float* __restrict__ out) {
    __shared__ float lds[4][64 * 11];
    int w = threadIdx.x >> 6;
    int l = threadIdx.x & 63;
    int a = blockIdx.x * 4 + w;
    float q = 1.0f + 0.1f * charges[a];

    {
        const float* mc = msg + ((size_t)a * 64 + l) * 10;
        float m0 = mc[0], m1 = mc[1], m2 = mc[2], m3 = mc[3], m4 = mc[4],
              m5 = mc[5], m6 = mc[6], m7 = mc[7], m8 = mc[8], m9 = mc[9];
        float M[9];
        M[0] = m0 + m4; M[1] = m5 + m1; M[2] = m6 + m2;
        M[3] = m5 - m1; M[4] = m0 + m7; M[5] = m8 + m3;
        M[6] = m6 - m2; M[7] = m8 - m3; M[8] = m0 + m9;
        const float* yp = Yb + ((size_t)a * 64 + l) * 9;
        float Y[9];
#pragma unroll
        for (int i = 0; i < 9; i++) Y[i] = yp[i];
        float P[9];
#pragma unroll
        for (int i = 0; i < 3; i++) {
#pragma unroll
            for (int j = 0; j < 3; j++) {
                float s = 0.f;
#pragma unroll
                for (int k = 0; k < 3; k++)
                    s += M[i * 3 + k] * Y[k * 3 + j] + Y[i * 3 + k] * M[k * 3 + j];
                P[i * 3 + j] = q * s;
            }
        }
        float t2 = 0.f;
#pragma unroll
        for (int i = 0; i < 9; i++) t2 += P[i] * P[i];
        float inv = 1.0f / (t2 + 1.0f);
        float iso = (P[0] + P[4] + P[8]) * (1.0f / 3.0f);
        float* o = &lds[w][l * 11];
        o[0] = iso * inv;
        o[1] = 0.5f * (P[1] - P[3]) * inv;
        o[2] = 0.5f * (P[2] - P[6]) * inv;
        o[3] = 0.5f * (P[5] - P[7]) * inv;
        o[4] = (P[0] - iso) * inv;
        o[5] = 0.5f * (P[1] + P[3]) * inv;
        o[6] = 0.5f * (P[2] + P[6]) * inv;
        o[7] = (P[4] - iso) * inv;
        o[8] = 0.5f * (P[5] + P[7]) * inv;
        o[9] = (P[8] - iso) * inv;
    }
    __syncthreads();
    {
        int g = l;
        const float* w3 = wtT + 3 * 4096;
        const float* w4 = wtT + 4 * 4096;
        const float* w5 = wtT + 5 * 4096;
        float acc[10];
#pragma unroll
        for (int c = 0; c < 10; c++) acc[c] = 0.f;
        for (int f = 0; f < 64; f++) {
            float wI = w3[f * 64 + g];
            float wA = w4[f * 64 + g];
            float wS = w5[f * 64 + g];
            const float* rf = &lds[w][f * 11];
            acc[0] += wI * rf[0];
            acc[1] += wA * rf[1];
            acc[2] += wA * rf[2];
            acc[3] += wA * rf[3];
#pragma unroll
            for (int c = 4; c < 10; c++) acc[c] += wS * rf[c];
        }
        float D[9];
        D[0] = acc[0] + acc[4]; D[1] = acc[5] + acc[1]; D[2] = acc[6] + acc[2];
        D[3] = acc[5] - acc[1]; D[4] = acc[0] + acc[7]; D[5] = acc[8] + acc[3];
        D[6] = acc[6] - acc[2]; D[7] = acc[8] - acc[3]; D[8] = acc[0] + acc[9];

        const float* x = X + ((size_t)a * 64 + g) * 9;
        float xv[9];
#pragma unroll
        for (int i = 0; i < 9; i++) xv[i] = x[i];
        float t2 = 0.f;
#pragma unroll
        for (int i = 0; i < 9; i++) t2 += xv[i] * xv[i];
        float invn = 1.0f / (t2 + 1.0f);
#pragma unroll
        for (int i = 0; i < 9; i++) xv[i] *= invn;

        float DD[9];
#pragma unroll
        for (int i = 0; i < 3; i++) {
#pragma unroll
            for (int j = 0; j < 3; j++) {
                float s = 0.f;
#pragma unroll
                for (int k = 0; k < 3; k++) s += D[i * 3 + k] * D[k * 3 + j];
                DD[i * 3 + j] = s;
            }
        }
        float* op = out + ((size_t)a * 64 + g) * 9;
#pragma unroll
        for (int i = 0; i < 9; i++) op[i] = xv[i] + D[i] + q * DD[i];
    }
}

extern "C" void kernel_launch(void* const* d_in, const int* in_sizes, int n_in,
                              void* d_out, int out_size, void* d_ws, size_t ws_size,
                              hipStream_t stream) {
    const float* X       = (const float*)d_in[0];
    const int*   pair    = (const int*)d_in[1];
    const float* dij     = (const float*)d_in[2];
    const float* rfv     = (const float*)d_in[3];
    const float* charges = (const float*)d_in[4];
    const float* W0      = (const float*)d_in[5];
    const float* b0      = (const float*)d_in[6];
    const float* W1      = (const float*)d_in[7];
    const float* b1      = (const float*)d_in[8];
    const float* W2      = (const float*)d_in[9];
    const float* b2      = (const float*)d_in[10];
    const float* Wt      = (const float*)d_in[11];
    float* out = (float*)d_out;

    const int* dst = pair;        // pair_indices[0] (scatter)
    const int* src = pair + NE;   // pair_indices[1] (gather)

    // ---- workspace layout (~228 MB) ----
    char* ws = (char*)d_ws;
    size_t ofs = 0;
    auto alloc = [&](size_t bytes) {
        void* p = ws + ofs;
        ofs += (bytes + 255) & ~(size_t)255;
        return p;
    };
    float* wtT  = (float*)alloc((size_t)6 * 4096 * 4);                 // 96 KB
    unsigned short* f0h = (unsigned short*)alloc(2048 * 2);
    unsigned short* f0l = (unsigned short*)alloc(2048 * 2);
    unsigned short* f1h = (unsigned short*)alloc(8192 * 2);
    unsigned short* f1l = (unsigned short*)alloc(8192 * 2);
    unsigned short* f2h = (unsigned short*)alloc(24576 * 2);
    unsigned short* f2l = (unsigned short*)alloc(24576 * 2);
    float* comp = (float*)alloc((size_t)N_ATOMS * FDIM * 10 * 4);      // 51.2 MB
    float* msg  = (float*)alloc((size_t)N_ATOMS * FDIM * 10 * 4);      // 51.2 MB
    __hip_bfloat16* rbuf = (__hip_bfloat16*)alloc((size_t)NE * 192 * 2); // 122.9 MB
    int* deg    = (int*)alloc((size_t)N_ATOMS * 4);
    int* offarr = (int*)alloc((size_t)(N_ATOMS + 1) * 4);
    int* cursor = (int*)alloc((size_t)N_ATOMS * 4);
    int* ebkt   = (int*)alloc((size_t)NE * 4);
    int* sbkt   = (int*)alloc((size_t)NE * 4);
    float* Yb   = out;  // reuse d_out as Y scratch; fully overwritten by lin2

    hipMemsetAsync(deg, 0, (size_t)N_ATOMS * 4, stream);
    hipMemsetAsync(cursor, 0, (size_t)N_ATOMS * 4, stream);

    transpose_kernel<<<(24576 + 255) / 256, 256, 0, stream>>>(Wt, wtT);
    wfrag_kernel<<<(34816 + 255) / 256, 256, 0, stream>>>(
        W0, W1, W2, f0h, f0l, f1h, f1l, f2h, f2l);
    hist_kernel<<<NE / 256, 256, 0, stream>>>(dst, deg);
    scan_kernel<<<1, 1024, 0, stream>>>(deg, offarr);
    fill_kernel<<<NE / 256, 256, 0, stream>>>(dst, src, offarr, cursor, ebkt, sbkt);

    mlp_mfma_kernel<<<NE / 64, 128, 0, stream>>>(
        rfv, dij, b0, b1, b2, f0h, f0l, f1h, f1l, f2h, f2l, rbuf);

    lin1_kernel<<<N_ATOMS / 4, 256, 0, stream>>>(X, wtT, comp, Yb);

    msg_kernel<<<N_ATOMS / 4, 256, 0, stream>>>(offarr, ebkt, sbkt, rbuf, comp, msg);

    lin2_kernel<<<N_ATOMS / 4, 256, 0, stream>>>(msg, Yb, X, charges, wtT, out);
}